// Round 1
// baseline (2392.700 us; speedup 1.0000x reference)
//
#include <hip/hip_runtime.h>

// Problem constants
#define T_STEPS 16
#define NB 8
#define CCH 64
#define HH 64
#define WW 64
#define HW (HH * WW)            // 4096
#define CHW (CCH * HW)          // 262144
#define NCHW (NB * CHW)         // 2097152
#define XTSTRIDE (NB * 2 * CCH * HW)  // per-timestep xt stride (N, 2C, H, W)

// ---------------------------------------------------------------------------
// Shared 3x3 conv tile: block = 256 threads, tile = 4 rows x 64 cols x 16 co.
// Loops over input channels in chunks of 8, staging input rows and weights in
// LDS. Each thread register-blocks 4 co x 4 rows at one column.
// ---------------------------------------------------------------------------
__device__ __forceinline__ void conv3x3_tile(
    const float* __restrict__ inp,   // NCHW conv input
    const float* __restrict__ wgt,   // [64][64][3][3] OIHW
    int n, int y0, int co0, int x, int cog, int tid,
    float acc[4][4])
{
    __shared__ __align__(16) float s_in[8][6][66];
    __shared__ __align__(16) float s_w[8][16][16];

    for (int cc = 0; cc < CCH; cc += 8) {
        // zero the left/right halo columns
        if (tid < 48) {
            int ci = tid / 6, r = tid % 6;
            s_in[ci][r][0]  = 0.0f;
            s_in[ci][r][65] = 0.0f;
        }
        // stage input: 8 ci x 6 rows x 64 cols (rows y0-1 .. y0+4, zero-padded)
        #pragma unroll
        for (int it = 0; it < 12; ++it) {
            int i   = tid + it * 256;
            int ci  = i / 384;
            int rem = i - ci * 384;
            int r   = rem >> 6;
            int xx  = rem & 63;
            int gy  = y0 - 1 + r;
            float v = 0.0f;
            if (gy >= 0 && gy < HH)
                v = inp[((n * CCH + cc + ci) * HH + gy) * WW + xx];
            s_in[ci][r][xx + 1] = v;
        }
        // stage weights: 8 ci x 16 co x 9 (padded to 16 for aligned float4)
        for (int i = tid; i < 8 * 16 * 9; i += 256) {
            int ci  = i / 144;
            int rem = i - ci * 144;
            int co  = rem / 9;
            int k   = rem - co * 9;
            s_w[ci][co][k] = wgt[((co0 + co) * CCH + cc + ci) * 9 + k];
        }
        __syncthreads();

        for (int ci = 0; ci < 8; ++ci) {
            float iv[6][3];
            #pragma unroll
            for (int r = 0; r < 6; ++r)
                #pragma unroll
                for (int dx = 0; dx < 3; ++dx)
                    iv[r][dx] = s_in[ci][r][x + dx];
            #pragma unroll
            for (int cl = 0; cl < 4; ++cl) {
                const float* wp = &s_w[ci][cog * 4 + cl][0];
                float4 wA = *(const float4*)(wp);
                float4 wB = *(const float4*)(wp + 4);
                float  w8 = wp[8];
                #pragma unroll
                for (int r = 0; r < 4; ++r) {
                    float s = acc[cl][r];
                    s = fmaf(wA.x, iv[r + 0][0], s);
                    s = fmaf(wA.y, iv[r + 0][1], s);
                    s = fmaf(wA.z, iv[r + 0][2], s);
                    s = fmaf(wA.w, iv[r + 1][0], s);
                    s = fmaf(wB.x, iv[r + 1][1], s);
                    s = fmaf(wB.y, iv[r + 1][2], s);
                    s = fmaf(wB.z, iv[r + 2][0], s);
                    s = fmaf(wB.w, iv[r + 2][1], s);
                    s = fmaf(w8,   iv[r + 2][2], s);
                    acc[cl][r] = s;
                }
            }
        }
        __syncthreads();
    }
}

// ---------------------------------------------------------------------------
// Kernel A: forget_gate = sigmoid(conv(prev_y, w_rz) + b_rz + xi_i)
//           a = prev_y * forget_gate
// prev_y is read from the ys output slab of step t-1 (zeros at t=0).
// ---------------------------------------------------------------------------
template <bool ZERO_IN>
__global__ __launch_bounds__(256, 2) void kA(
    const float* __restrict__ yprev, const float* __restrict__ w_rz,
    const float* __restrict__ b_rz, const float* __restrict__ xt_t,
    float* __restrict__ f_out, float* __restrict__ a_out)
{
    int tid = threadIdx.x;
    int x   = tid & 63;
    int cog = tid >> 6;
    int bid = blockIdx.x;
    int n     = bid >> 6;
    int strip = (bid >> 2) & 15;
    int co0   = (bid & 3) * 16;
    int y0    = strip * 4;

    float acc[4][4] = {};
    if (!ZERO_IN)
        conv3x3_tile(yprev, w_rz, n, y0, co0, x, cog, tid, acc);

    #pragma unroll
    for (int cl = 0; cl < 4; ++cl) {
        int   co   = co0 + cog * 4 + cl;
        float bias = b_rz[co];
        #pragma unroll
        for (int r = 0; r < 4; ++r) {
            int gy  = y0 + r;
            int idx = ((n * CCH + co) * HH + gy) * WW + x;
            float xi = xt_t[(n * 2 * CCH + co) * HW + gy * WW + x];
            float s  = acc[cl][r] + bias + xi;
            float f  = 1.0f / (1.0f + expf(-s));
            float py = ZERO_IN ? 0.0f : yprev[idx];
            f_out[idx] = f;
            a_out[idx] = py * f;
        }
    }
}

// ---------------------------------------------------------------------------
// Kernel B: g = tanh(conv(a, w_f) + b_f + xi_f), then the GRU/spike update.
// Writes ys/events/neg_dists for step t and the new h into the ws h-buffer.
// ---------------------------------------------------------------------------
__global__ __launch_bounds__(256, 2) void kB(
    const float* __restrict__ a_in, const float* __restrict__ w_f,
    const float* __restrict__ b_f, const float* __restrict__ xt_t,
    const float* __restrict__ f_in, const float* __restrict__ thr_rp,
    float* __restrict__ h_buf,
    float* __restrict__ ys, float* __restrict__ ev, float* __restrict__ nd)
{
    int tid = threadIdx.x;
    int x   = tid & 63;
    int cog = tid >> 6;
    int bid = blockIdx.x;
    int n     = bid >> 6;
    int strip = (bid >> 2) & 15;
    int co0   = (bid & 3) * 16;
    int y0    = strip * 4;

    float acc[4][4] = {};
    conv3x3_tile(a_in, w_f, n, y0, co0, x, cog, tid, acc);

    float thrv[4];
    #pragma unroll
    for (int r = 0; r < 4; ++r)
        thrv[r] = 1.0f / (1.0f + expf(-thr_rp[(y0 + r) * WW + x]));

    #pragma unroll
    for (int cl = 0; cl < 4; ++cl) {
        int   co   = co0 + cog * 4 + cl;
        float bias = b_f[co];
        #pragma unroll
        for (int r = 0; r < 4; ++r) {
            int gy  = y0 + r;
            int idx = ((n * CCH + co) * HH + gy) * WW + x;
            float xi = xt_t[(n * 2 * CCH + CCH + co) * HW + gy * WW + x];
            float g  = tanhf(acc[cl][r] + bias + xi);
            float f  = f_in[idx];
            float hp = h_buf[idx];
            float h  = (1.0f - f) * hp + f * g;
            float thr = thrv[r];
            float d   = h - thr;
            bool  e   = d > 0.0f;
            ys[idx] = e ? h : 0.0f;
            ev[idx] = e ? 1.0f : 0.0f;
            nd[idx] = (d < 0.0f) ? (thr - h) : 0.0f;
            h_buf[idx] = e ? d : h;   // h - event*thr
        }
    }
}

// ---------------------------------------------------------------------------
extern "C" void kernel_launch(void* const* d_in, const int* in_sizes, int n_in,
                              void* d_out, int out_size, void* d_ws, size_t ws_size,
                              hipStream_t stream)
{
    (void)in_sizes; (void)n_in; (void)out_size; (void)ws_size;

    const float* xt     = (const float*)d_in[0];
    const float* w_rz   = (const float*)d_in[1];
    const float* b_rz   = (const float*)d_in[2];
    const float* w_f    = (const float*)d_in[3];
    const float* b_f    = (const float*)d_in[4];
    const float* thr_rp = (const float*)d_in[5];

    float* out   = (float*)d_out;
    float* h_buf = (float*)d_ws;               // NCHW
    float* f_buf = h_buf + NCHW;               // NCHW
    float* a_buf = f_buf + NCHW;               // NCHW

    float* ys0 = out;
    float* ev0 = out + (size_t)T_STEPS * NCHW;
    float* nd0 = ev0 + (size_t)T_STEPS * NCHW;

    hipMemsetAsync(h_buf, 0, (size_t)NCHW * sizeof(float), stream);

    dim3 grid(512), block(256);
    for (int t = 0; t < T_STEPS; ++t) {
        const float* xt_t  = xt + (size_t)t * XTSTRIDE;
        const float* yprev = (t == 0) ? nullptr : (ys0 + (size_t)(t - 1) * NCHW);
        if (t == 0)
            kA<true><<<grid, block, 0, stream>>>(yprev, w_rz, b_rz, xt_t, f_buf, a_buf);
        else
            kA<false><<<grid, block, 0, stream>>>(yprev, w_rz, b_rz, xt_t, f_buf, a_buf);
        kB<<<grid, block, 0, stream>>>(a_buf, w_f, b_f, xt_t, f_buf, thr_rp, h_buf,
                                       ys0 + (size_t)t * NCHW,
                                       ev0 + (size_t)t * NCHW,
                                       nd0 + (size_t)t * NCHW);
    }
}

// Round 2
// 1196.702 us; speedup vs baseline: 1.9994x; 1.9994x over previous
//
#include <hip/hip_runtime.h>
#include <cstdint>

typedef _Float16 half8 __attribute__((ext_vector_type(8)));
typedef float f32x4 __attribute__((ext_vector_type(4)));

#define T_STEPS 16
#define NB 8
#define CCH 64
#define HH 64
#define WW 64
#define HW (HH * WW)                   // 4096
#define NCHW (NB * CCH * HW)           // 2097152
#define XTSTR (NB * 2 * CCH * HW)      // per-timestep xt stride

// LDS geometry: input [4 rows][66 cols][40 ci-pad] f16 per split (80B stride, 16B aligned)
#define CI_PAD 40
#define IN_LDS (4 * 66 * CI_PAD)       // 10560 halves = 21120 B per split

__device__ __forceinline__ unsigned short h_bits(_Float16 h) {
    union { _Float16 h; unsigned short u; } v; v.h = h; return v.u;
}

// fp32 -> f16 hi + f16 lo*2048 split (fp32-equivalent when recombined hi + lo/2048)
__device__ __forceinline__ void split2(float x, unsigned short& hb, unsigned short& lb) {
    _Float16 hi = (_Float16)x;
    _Float16 lo = (_Float16)((x - (float)hi) * 2048.0f);
    hb = h_bits(hi); lb = h_bits(lo);
}

// ---------------------------------------------------------------------------
// Weight pipeline: load 8 taps-strided f32 into regs; later split+write to LDS.
// Thread t: co = t>>2, cig = t&3 -> 8 consecutive ci of chunk. Swizzle cig^co&3.
// ---------------------------------------------------------------------------
__device__ __forceinline__ void load_w(const float* __restrict__ wgt, int tap, int chunk,
                                       int tid, float* wr) {
    int co = tid >> 2, cig = tid & 3;
    const float* p = wgt + ((size_t)co * CCH + chunk * 32 + cig * 8) * 9 + tap;
    #pragma unroll
    for (int j = 0; j < 8; ++j) wr[j] = p[j * 9];
}

__device__ __forceinline__ void write_w(const float* wr, _Float16* dh, _Float16* dl, int tid) {
    int co = tid >> 2, cig = tid & 3;
    unsigned short hb[8], lb[8];
    #pragma unroll
    for (int j = 0; j < 8; ++j) split2(wr[j], hb[j], lb[j]);
    uint32_t hw[4], lw[4];
    #pragma unroll
    for (int q = 0; q < 4; ++q) {
        hw[q] = (uint32_t)hb[2*q] | ((uint32_t)hb[2*q+1] << 16);
        lw[q] = (uint32_t)lb[2*q] | ((uint32_t)lb[2*q+1] << 16);
    }
    int off = co * 32 + (cig ^ (co & 3)) * 8;
    *(uint4*)&dh[off] = make_uint4(hw[0], hw[1], hw[2], hw[3]);
    *(uint4*)&dl[off] = make_uint4(lw[0], lw[1], lw[2], lw[3]);
}

// ---------------------------------------------------------------------------
// Input staging (transposed + split): SRC=0 from fp32 NCHW (prev ys slab),
// SRC=1 from packed u32 (hi<<16|lo) [n][row][col][ci] buffer.
// Fills s_hi/s_lo: [r 0..3][c 0..65][ci-pad 40], rows y0-1..y0+2, zero halo.
// ---------------------------------------------------------------------------
template<int SRC>
__device__ __forceinline__ void stage_input(const void* __restrict__ src, int n, int y0,
                                            int chunk, _Float16* s_hi, _Float16* s_lo, int tid)
{
    for (int i = tid; i < 4 * 4 * 66; i += 256) {
        int r   = i / 264;
        int rem = i - r * 264;
        int gg  = rem / 66;
        int c   = rem - gg * 66;
        int gr  = y0 - 1 + r;
        int gc  = c - 1;
        bool ok = (gr >= 0) & (gr < HH) & (gc >= 0) & (gc < WW);
        uint32_t hw[4], lw[4];
        if (SRC == 0) {
            unsigned short hb[8], lb[8];
            if (ok) {
                const float* yp = (const float*)src;
                #pragma unroll
                for (int j = 0; j < 8; ++j) {
                    int ci = chunk * 32 + gg * 8 + j;
                    float v = yp[(((size_t)n * CCH + ci) * HH + gr) * WW + gc];
                    split2(v, hb[j], lb[j]);
                }
            } else {
                #pragma unroll
                for (int j = 0; j < 8; ++j) { hb[j] = 0; lb[j] = 0; }
            }
            #pragma unroll
            for (int q = 0; q < 4; ++q) {
                hw[q] = (uint32_t)hb[2*q] | ((uint32_t)hb[2*q+1] << 16);
                lw[q] = (uint32_t)lb[2*q] | ((uint32_t)lb[2*q+1] << 16);
            }
        } else {
            uint32_t u[8];
            if (ok) {
                const uint32_t* p = (const uint32_t*)src +
                    (((size_t)n * HH + gr) * WW + gc) * CCH + chunk * 32 + gg * 8;
                uint4 u0 = *(const uint4*)(p);
                uint4 u1 = *(const uint4*)(p + 4);
                u[0]=u0.x; u[1]=u0.y; u[2]=u0.z; u[3]=u0.w;
                u[4]=u1.x; u[5]=u1.y; u[6]=u1.z; u[7]=u1.w;
            } else {
                #pragma unroll
                for (int j = 0; j < 8; ++j) u[j] = 0;
            }
            #pragma unroll
            for (int q = 0; q < 4; ++q) {
                hw[q] = (u[2*q] >> 16) | (u[2*q+1] & 0xFFFF0000u);
                lw[q] = (u[2*q] & 0xFFFFu) | (u[2*q+1] << 16);
            }
        }
        int off = (r * 66 + c) * CI_PAD + gg * 8;
        *(uint4*)&s_hi[off] = make_uint4(hw[0], hw[1], hw[2], hw[3]);
        *(uint4*)&s_lo[off] = make_uint4(lw[0], lw[1], lw[2], lw[3]);
    }
}

// ---------------------------------------------------------------------------
// MFMA conv core: accumulates full 3x3x64 conv for this block's 64co x 128sp
// tile into acc1 (hi*hi) and acc2 (cross terms, x2048 scale).
// ---------------------------------------------------------------------------
template<int SRC>
__device__ __forceinline__ void conv_mfma(
    const void* __restrict__ src, const float* __restrict__ wgt,
    int n, int y0, int tid,
    f32x4 acc1[4][2], f32x4 acc2[4][2],
    _Float16* s_in_h, _Float16* s_in_l, _Float16 (*s_w)[2][2048])
{
    int wv = tid >> 6, l = tid & 63, lg = l >> 4, ln = l & 15;

    stage_input<SRC>(src, n, y0, 0, s_in_h, s_in_l, tid);
    {   // direct-stage weights for ks=0
        float wr0[8];
        load_w(wgt, 0, 0, tid, wr0);
        write_w(wr0, s_w[0][0], s_w[0][1], tid);
    }
    float wreg[8];                       // holds weights for kstep ks+1
    load_w(wgt, 1, 0, tid, wreg);
    __syncthreads();

    int db = 0;
    int aoff = ln * 32 + (lg ^ (ln & 3)) * 8;   // A-frag swizzled base (per cotile add 16*32)
    for (int ks = 0; ks < 18; ++ks) {
        int tap = ks >= 9 ? ks - 9 : ks;
        int dy = tap / 3 - 1, dx = tap - (tap / 3) * 3 - 1;

        half8 af[2][4];
        #pragma unroll
        for (int s = 0; s < 2; ++s)
            #pragma unroll
            for (int ct = 0; ct < 4; ++ct)
                af[s][ct] = *(const half8*)&s_w[db][s][ct * 16 * 32 + aoff];

        half8 bf[2][2];
        #pragma unroll
        for (int st = 0; st < 2; ++st) {
            int sp   = wv * 32 + st * 16 + ln;
            int r_in = (sp >> 6) + dy + 1;
            int c_in = (sp & 63) + dx + 1;
            int boff = (r_in * 66 + c_in) * CI_PAD + lg * 8;
            bf[0][st] = *(const half8*)&s_in_h[boff];
            bf[1][st] = *(const half8*)&s_in_l[boff];
        }

        #pragma unroll
        for (int ct = 0; ct < 4; ++ct)
            #pragma unroll
            for (int st = 0; st < 2; ++st) {
                acc1[ct][st] = __builtin_amdgcn_mfma_f32_16x16x32_f16(af[0][ct], bf[0][st], acc1[ct][st], 0, 0, 0);
                acc2[ct][st] = __builtin_amdgcn_mfma_f32_16x16x32_f16(af[0][ct], bf[1][st], acc2[ct][st], 0, 0, 0);
                acc2[ct][st] = __builtin_amdgcn_mfma_f32_16x16x32_f16(af[1][ct], bf[0][st], acc2[ct][st], 0, 0, 0);
            }

        if (ks < 17) write_w(wreg, s_w[db ^ 1][0], s_w[db ^ 1][1], tid);
        __syncthreads();
        if (ks == 8) {   // chunk boundary: restage input with ci 32..63
            stage_input<SRC>(src, n, y0, 1, s_in_h, s_in_l, tid);
            __syncthreads();
        }
        if (ks + 2 < 18) {   // issue next-next weight loads (drained at NEXT barrier)
            int nk = ks + 2;
            int nc = nk >= 9 ? 1 : 0;
            load_w(wgt, nk - nc * 9, nc, tid, wreg);
        }
        db ^= 1;
    }
}

// ---------------------------------------------------------------------------
// Kernel A: f = sigmoid(conv(prev_y, w_rz) + b_rz + xi_i); a = prev_y * f.
// Writes f (fp32) and a as packed hi|lo f16 pairs [n][row][col][ci].
// ---------------------------------------------------------------------------
template<bool ZERO>
__global__ __launch_bounds__(256, 1) void kA(
    const float* __restrict__ yprev, const float* __restrict__ w_rz,
    const float* __restrict__ b_rz, const float* __restrict__ xt_t,
    float* __restrict__ f_out, uint32_t* __restrict__ a_pack)
{
    __shared__ __align__(16) _Float16 s_in_h[IN_LDS];
    __shared__ __align__(16) _Float16 s_in_l[IN_LDS];
    __shared__ __align__(16) _Float16 s_w[2][2][2048];

    int tid = threadIdx.x;
    int wv = tid >> 6, l = tid & 63, lg = l >> 4, ln = l & 15;
    int bid = blockIdx.x;
    int n = bid >> 5, y0 = (bid & 31) * 2;

    f32x4 acc1[4][2] = {}; f32x4 acc2[4][2] = {};
    if (!ZERO)
        conv_mfma<0>(yprev, w_rz, n, y0, tid, acc1, acc2, s_in_h, s_in_l, s_w);

    #pragma unroll
    for (int ct = 0; ct < 4; ++ct)
        #pragma unroll
        for (int st = 0; st < 2; ++st) {
            int sp = wv * 32 + st * 16 + ln;
            int row = y0 + (sp >> 6), col = sp & 63;
            uint32_t pk[4];
            #pragma unroll
            for (int r = 0; r < 4; ++r) {
                int co = ct * 16 + lg * 4 + r;
                float conv = ZERO ? 0.0f
                    : (acc1[ct][st][r] + acc2[ct][st][r] * (1.0f / 2048.0f));
                int idx = ((n * CCH + co) * HH + row) * WW + col;
                float s = conv + b_rz[co] + xt_t[((n * 2 * CCH + co) * HH + row) * WW + col];
                float f = 1.0f / (1.0f + expf(-s));
                float py = ZERO ? 0.0f : yprev[idx];
                f_out[idx] = f;
                float a = py * f;
                unsigned short hb, lb; split2(a, hb, lb);
                pk[r] = ((uint32_t)hb << 16) | lb;
            }
            if (!ZERO) {
                uint32_t* dst = &a_pack[(((size_t)n * HH + row) * WW + col) * CCH
                                        + ct * 16 + lg * 4];
                *(uint4*)dst = make_uint4(pk[0], pk[1], pk[2], pk[3]);
            }
        }
}

// ---------------------------------------------------------------------------
// Kernel B: g = tanh(conv(a, w_f) + b_f + xi_f); GRU/spike update + outputs.
// ---------------------------------------------------------------------------
template<bool ZERO>
__global__ __launch_bounds__(256, 1) void kB(
    const uint32_t* __restrict__ a_pack, const float* __restrict__ w_f,
    const float* __restrict__ b_f, const float* __restrict__ xt_t,
    const float* __restrict__ f_in, const float* __restrict__ thr_rp,
    float* __restrict__ h_buf, float* __restrict__ ys,
    float* __restrict__ ev, float* __restrict__ nd)
{
    __shared__ __align__(16) _Float16 s_in_h[IN_LDS];
    __shared__ __align__(16) _Float16 s_in_l[IN_LDS];
    __shared__ __align__(16) _Float16 s_w[2][2][2048];

    int tid = threadIdx.x;
    int wv = tid >> 6, l = tid & 63, lg = l >> 4, ln = l & 15;
    int bid = blockIdx.x;
    int n = bid >> 5, y0 = (bid & 31) * 2;

    f32x4 acc1[4][2] = {}; f32x4 acc2[4][2] = {};
    if (!ZERO)
        conv_mfma<1>(a_pack, w_f, n, y0, tid, acc1, acc2, s_in_h, s_in_l, s_w);

    #pragma unroll
    for (int ct = 0; ct < 4; ++ct)
        #pragma unroll
        for (int st = 0; st < 2; ++st) {
            int sp = wv * 32 + st * 16 + ln;
            int row = y0 + (sp >> 6), col = sp & 63;
            float thr = 1.0f / (1.0f + expf(-thr_rp[row * WW + col]));
            #pragma unroll
            for (int r = 0; r < 4; ++r) {
                int co = ct * 16 + lg * 4 + r;
                float conv = ZERO ? 0.0f
                    : (acc1[ct][st][r] + acc2[ct][st][r] * (1.0f / 2048.0f));
                int idx = ((n * CCH + co) * HH + row) * WW + col;
                float s = conv + b_f[co]
                        + xt_t[((n * 2 * CCH + CCH + co) * HH + row) * WW + col];
                float e2 = expf(2.0f * s);
                float g  = 1.0f - 2.0f / (e2 + 1.0f);     // tanh(s)
                float f  = f_in[idx];
                float hp = ZERO ? 0.0f : h_buf[idx];
                float h  = (1.0f - f) * hp + f * g;
                float d  = h - thr;
                bool  e  = d > 0.0f;
                ys[idx] = e ? h : 0.0f;
                ev[idx] = e ? 1.0f : 0.0f;
                nd[idx] = (d < 0.0f) ? (thr - h) : 0.0f;
                h_buf[idx] = e ? d : h;                   // h - event*thr
            }
        }
}

// ---------------------------------------------------------------------------
extern "C" void kernel_launch(void* const* d_in, const int* in_sizes, int n_in,
                              void* d_out, int out_size, void* d_ws, size_t ws_size,
                              hipStream_t stream)
{
    (void)in_sizes; (void)n_in; (void)out_size; (void)ws_size;

    const float* xt     = (const float*)d_in[0];
    const float* w_rz   = (const float*)d_in[1];
    const float* b_rz   = (const float*)d_in[2];
    const float* w_f    = (const float*)d_in[3];
    const float* b_f    = (const float*)d_in[4];
    const float* thr_rp = (const float*)d_in[5];

    float* out    = (float*)d_out;
    float* h_buf  = (float*)d_ws;                    // 2M f32 = 8 MB
    float* f_buf  = h_buf + NCHW;                    // 2M f32 = 8 MB
    uint32_t* a_pack = (uint32_t*)(f_buf + NCHW);    // 2M u32 = 8 MB  (total 24 MB)

    float* ys0 = out;
    float* ev0 = out + (size_t)T_STEPS * NCHW;
    float* nd0 = ev0 + (size_t)T_STEPS * NCHW;

    dim3 grid(256), block(256);
    for (int t = 0; t < T_STEPS; ++t) {
        const float* xt_t  = xt + (size_t)t * XTSTR;
        float* ys_t = ys0 + (size_t)t * NCHW;
        if (t == 0) {
            kA<true><<<grid, block, 0, stream>>>(ys0, w_rz, b_rz, xt_t, f_buf, a_pack);
            kB<true><<<grid, block, 0, stream>>>(a_pack, w_f, b_f, xt_t, f_buf, thr_rp,
                                                 h_buf, ys_t,
                                                 ev0 + (size_t)t * NCHW,
                                                 nd0 + (size_t)t * NCHW);
        } else {
            const float* yprev = ys0 + (size_t)(t - 1) * NCHW;
            kA<false><<<grid, block, 0, stream>>>(yprev, w_rz, b_rz, xt_t, f_buf, a_pack);
            kB<false><<<grid, block, 0, stream>>>(a_pack, w_f, b_f, xt_t, f_buf, thr_rp,
                                                  h_buf, ys_t,
                                                  ev0 + (size_t)t * NCHW,
                                                  nd0 + (size_t)t * NCHW);
        }
    }
}

// Round 3
// 775.024 us; speedup vs baseline: 3.0873x; 1.5441x over previous
//
#include <hip/hip_runtime.h>
#include <cstdint>

typedef _Float16 half8 __attribute__((ext_vector_type(8)));
typedef float f32x4 __attribute__((ext_vector_type(4)));

#define T_STEPS 16
#define NB 8
#define CCH 64
#define HH 64
#define WW 64
#define HW 4096
#define NCHW (NB * CCH * HW)          // 2097152
#define XTSTR (NB * 2 * CCH * HW)

#define CI_PAD 40                      // halves per (r,c) cell: 80B stride, 16B aligned
#define IN_LDS (4 * 66 * CI_PAD)

__device__ __forceinline__ unsigned short h_bits(_Float16 h) {
    union { _Float16 h; unsigned short u; } v; v.h = h; return v.u;
}
// fp32 -> f16 hi + f16 (residual*2048); recombine hi + lo/2048 ~ fp32-exact
__device__ __forceinline__ void split2(float x, unsigned short& hb, unsigned short& lb) {
    _Float16 hi = (_Float16)x;
    _Float16 lo = (_Float16)((x - (float)hi) * 2048.0f);
    hb = h_bits(hi); lb = h_bits(lo);
}
__device__ __forceinline__ uint32_t pack2(float x) {
    unsigned short h, l; split2(x, h, l); return ((uint32_t)h << 16) | l;
}

// ---------------------------------------------------------------------------
// One-time weight prepack: wpack[g][tap][chunk][ch][co32][ci32] = hi<<16|lo
// ---------------------------------------------------------------------------
__global__ __launch_bounds__(256) void prep_w(const float* __restrict__ w_rz,
                                              const float* __restrict__ w_f,
                                              uint32_t* __restrict__ wpack) {
    int i = blockIdx.x * 256 + threadIdx.x;
    if (i >= 2 * 9 * 2 * 2 * 32 * 32) return;
    int ci = i & 31, co = (i >> 5) & 31, ch = (i >> 10) & 1, chunk = (i >> 11) & 1;
    int gt = i >> 12; int tap = gt % 9; int g = gt / 9;
    const float* w = g ? w_f : w_rz;
    float v = w[(size_t)((ch * 32 + co) * CCH + (chunk * 32 + ci)) * 9 + tap];
    wpack[i] = pack2(v);
}

// ---------------------------------------------------------------------------
// Stage one ci-chunk (32) of packed input into split LDS. Coalesced: lanes
// i&3 = ci-granule -> 4 lanes read 128B contiguous.
// ---------------------------------------------------------------------------
__device__ __forceinline__ void stage_pk(const uint32_t* __restrict__ pk, int n, int y0,
                                         int chunk, _Float16* __restrict__ s_hi,
                                         _Float16* __restrict__ s_lo, int tid) {
    #pragma unroll
    for (int it = 0; it < 5; ++it) {
        int i = tid + it * 256;
        if (i >= 1056) break;                 // 4 rows x 66 cols x 4 granules
        int gg = i & 3; int tmp = i >> 2; int c = tmp % 66; int r = tmp / 66;
        int gr = y0 - 1 + r, gc = c - 1;
        uint4 ua = make_uint4(0,0,0,0), ub = make_uint4(0,0,0,0);
        if ((unsigned)gr < 64u && (unsigned)gc < 64u) {
            const uint32_t* p = pk + ((((size_t)n * 64 + gr) * 64 + gc) * 64
                                      + chunk * 32 + gg * 8);
            ua = *(const uint4*)p; ub = *(const uint4*)(p + 4);
        }
        uint32_t hw0 = (ua.x >> 16) | (ua.y & 0xFFFF0000u), lw0 = (ua.x & 0xFFFFu) | (ua.y << 16);
        uint32_t hw1 = (ua.z >> 16) | (ua.w & 0xFFFF0000u), lw1 = (ua.z & 0xFFFFu) | (ua.w << 16);
        uint32_t hw2 = (ub.x >> 16) | (ub.y & 0xFFFF0000u), lw2 = (ub.x & 0xFFFFu) | (ub.y << 16);
        uint32_t hw3 = (ub.z >> 16) | (ub.w & 0xFFFF0000u), lw3 = (ub.z & 0xFFFFu) | (ub.w << 16);
        int off = (r * 66 + c) * CI_PAD + gg * 8;
        *(uint4*)&s_hi[off] = make_uint4(hw0, hw1, hw2, hw3);
        *(uint4*)&s_lo[off] = make_uint4(lw0, lw1, lw2, lw3);
    }
}

// ---------------------------------------------------------------------------
// Weight group (3 taps, one ci-chunk, one co-half): coalesced uint4/thread.
// ---------------------------------------------------------------------------
__device__ __forceinline__ void wload(const uint32_t* __restrict__ wp, int gi, int ch,
                                      int tid, uint4* u) {
    int chunk = gi / 3, ty = gi - chunk * 3;
    #pragma unroll
    for (int tx = 0; tx < 3; ++tx) {
        const uint32_t* p = wp + (size_t)(((ty * 3 + tx) * 2 + chunk) * 2 + ch) * 1024
                          + tid * 4;
        u[tx] = *(const uint4*)p;
    }
}

__device__ __forceinline__ void wwrite(const uint4* u, _Float16 (*sw)[2][1024], int tid) {
    int co = tid >> 3, j = tid & 7;
    int pos = ((j >> 1) ^ (co ^ (co >> 2))) & 3;       // granule swizzle
    int off = co * 32 + pos * 8 + (j & 1) * 4;
    #pragma unroll
    for (int tx = 0; tx < 3; ++tx) {
        uint4 q = u[tx];
        uint32_t hw0 = (q.x >> 16) | (q.y & 0xFFFF0000u), lw0 = (q.x & 0xFFFFu) | (q.y << 16);
        uint32_t hw1 = (q.z >> 16) | (q.w & 0xFFFF0000u), lw1 = (q.z & 0xFFFFu) | (q.w << 16);
        *(uint2*)&sw[tx][0][off] = make_uint2(hw0, hw1);
        *(uint2*)&sw[tx][1][off] = make_uint2(lw0, lw1);
    }
}

// ---------------------------------------------------------------------------
// Conv core: 32co x 128sp tile, K = 2 chunks x 3 ty-groups x 3 tx taps.
// One barrier per 3-tap group (plus one restage barrier). Split-f16 MFMA.
// ---------------------------------------------------------------------------
__device__ __forceinline__ void conv_core(const uint32_t* __restrict__ in_pk,
    const uint32_t* __restrict__ wp, int n, int y0, int ch, int tid,
    f32x4 acc1[2][2], f32x4 acc2[2][2],
    _Float16* s_in_h, _Float16* s_in_l, _Float16 (*s_w)[3][2][1024]) {

    int wv = tid >> 6, l = tid & 63, lg = l >> 4, ln = l & 15;
    int aoff = ln * 32 + ((lg ^ ln ^ (ln >> 2)) & 3) * 8;

    uint4 wreg[3];
    stage_pk(in_pk, n, y0, 0, s_in_h, s_in_l, tid);
    wload(wp, 0, ch, tid, wreg);
    wwrite(wreg, s_w[0], tid);
    wload(wp, 1, ch, tid, wreg);
    __syncthreads();

    int db = 0;
    for (int gi = 0; gi < 6; ++gi) {
        int ty = gi % 3;
        if (gi < 5) {                       // write next group's weights, prefetch g+2
            wwrite(wreg, s_w[db ^ 1], tid);
            if (gi + 2 < 6) wload(wp, gi + 2, ch, tid, wreg);
        }
        #pragma unroll
        for (int tx = 0; tx < 3; ++tx) {
            half8 afh[2], afl[2];
            #pragma unroll
            for (int ct = 0; ct < 2; ++ct) {
                afh[ct] = *(const half8*)&s_w[db][tx][0][ct * 512 + aoff];
                afl[ct] = *(const half8*)&s_w[db][tx][1][ct * 512 + aoff];
            }
            half8 bfh[2], bfl[2];
            #pragma unroll
            for (int st = 0; st < 2; ++st) {
                int sp = wv * 32 + st * 16 + ln;
                int boff = (((sp >> 6) + ty) * 66 + (sp & 63) + tx) * CI_PAD + lg * 8;
                bfh[st] = *(const half8*)&s_in_h[boff];
                bfl[st] = *(const half8*)&s_in_l[boff];
            }
            #pragma unroll
            for (int ct = 0; ct < 2; ++ct)
                #pragma unroll
                for (int st = 0; st < 2; ++st) {
                    acc1[ct][st] = __builtin_amdgcn_mfma_f32_16x16x32_f16(afh[ct], bfh[st], acc1[ct][st], 0, 0, 0);
                    acc2[ct][st] = __builtin_amdgcn_mfma_f32_16x16x32_f16(afh[ct], bfl[st], acc2[ct][st], 0, 0, 0);
                    acc2[ct][st] = __builtin_amdgcn_mfma_f32_16x16x32_f16(afl[ct], bfh[st], acc2[ct][st], 0, 0, 0);
                }
        }
        if (gi == 2) {                       // chunk boundary: restage ci 32..63
            __syncthreads();
            stage_pk(in_pk, n, y0, 1, s_in_h, s_in_l, tid);
        }
        __syncthreads();
        db ^= 1;
    }
}

// ---------------------------------------------------------------------------
// Kernel A: f = sigmoid(conv(prev_y, w_rz) + b_rz + xi_i); a = prev_y * f.
// ---------------------------------------------------------------------------
template<bool ZERO>
__global__ __launch_bounds__(256, 2) void kA(
    const float* __restrict__ yprev, const uint32_t* __restrict__ ypk,
    const uint32_t* __restrict__ wpk, const float* __restrict__ b_rz,
    const float* __restrict__ xt_t, float* __restrict__ f_out,
    uint32_t* __restrict__ a_pack) {

    __shared__ __align__(16) _Float16 s_in_h[IN_LDS];
    __shared__ __align__(16) _Float16 s_in_l[IN_LDS];
    __shared__ __align__(16) _Float16 s_w[2][3][2][1024];

    int tid = threadIdx.x, wv = tid >> 6, l = tid & 63, lg = l >> 4, ln = l & 15;
    int bid = blockIdx.x;
    int n = bid >> 6, strip = (bid >> 1) & 31, ch = bid & 1, y0 = strip * 2;

    f32x4 acc1[2][2] = {}, acc2[2][2] = {};
    if (!ZERO)
        conv_core(ypk, wpk, n, y0, ch, tid, acc1, acc2, s_in_h, s_in_l, s_w);

    #pragma unroll
    for (int ct = 0; ct < 2; ++ct)
        #pragma unroll
        for (int st = 0; st < 2; ++st) {
            int sp = wv * 32 + st * 16 + ln, row = y0 + (sp >> 6), col = sp & 63;
            uint32_t pk[4];
            #pragma unroll
            for (int r = 0; r < 4; ++r) {
                int co = ch * 32 + ct * 16 + lg * 4 + r;
                float conv = ZERO ? 0.0f
                    : (acc1[ct][st][r] + acc2[ct][st][r] * (1.0f / 2048.0f));
                int idx = ((n * CCH + co) * HH + row) * WW + col;
                float xi = xt_t[((n * 2 * CCH + co) * HH + row) * WW + col];
                float s = conv + b_rz[co] + xi;
                float f = 1.0f / (1.0f + expf(-s));
                float py = ZERO ? 0.0f : yprev[idx];
                f_out[idx] = f;
                pk[r] = pack2(py * f);
            }
            if (!ZERO)
                *(uint4*)&a_pack[(((size_t)n * 64 + row) * 64 + col) * 64
                                 + ch * 32 + ct * 16 + lg * 4] =
                    make_uint4(pk[0], pk[1], pk[2], pk[3]);
        }
}

// ---------------------------------------------------------------------------
// Kernel B: g = tanh(conv(a, w_f) + b_f + xi_f); GRU/spike update; writes
// ys/ev/nd, h_buf, and packed y for next step's kA staging.
// ---------------------------------------------------------------------------
template<bool ZERO>
__global__ __launch_bounds__(256, 2) void kB(
    const uint32_t* __restrict__ a_pack, const uint32_t* __restrict__ wpk,
    const float* __restrict__ b_f, const float* __restrict__ xt_t,
    const float* __restrict__ f_in, const float* __restrict__ thr_rp,
    float* __restrict__ h_buf, float* __restrict__ ys,
    float* __restrict__ ev, float* __restrict__ nd,
    uint32_t* __restrict__ y_pack) {

    __shared__ __align__(16) _Float16 s_in_h[IN_LDS];
    __shared__ __align__(16) _Float16 s_in_l[IN_LDS];
    __shared__ __align__(16) _Float16 s_w[2][3][2][1024];

    int tid = threadIdx.x, wv = tid >> 6, l = tid & 63, lg = l >> 4, ln = l & 15;
    int bid = blockIdx.x;
    int n = bid >> 6, strip = (bid >> 1) & 31, ch = bid & 1, y0 = strip * 2;

    f32x4 acc1[2][2] = {}, acc2[2][2] = {};
    if (!ZERO)
        conv_core(a_pack, wpk, n, y0, ch, tid, acc1, acc2, s_in_h, s_in_l, s_w);

    #pragma unroll
    for (int ct = 0; ct < 2; ++ct)
        #pragma unroll
        for (int st = 0; st < 2; ++st) {
            int sp = wv * 32 + st * 16 + ln, row = y0 + (sp >> 6), col = sp & 63;
            float thr = 1.0f / (1.0f + expf(-thr_rp[row * WW + col]));
            uint32_t pk[4];
            #pragma unroll
            for (int r = 0; r < 4; ++r) {
                int co = ch * 32 + ct * 16 + lg * 4 + r;
                float conv = ZERO ? 0.0f
                    : (acc1[ct][st][r] + acc2[ct][st][r] * (1.0f / 2048.0f));
                int idx = ((n * CCH + co) * HH + row) * WW + col;
                float xi = xt_t[((n * 2 * CCH + CCH + co) * HH + row) * WW + col];
                float s  = conv + b_f[co] + xi;
                float e2 = expf(2.0f * s);
                float g  = 1.0f - 2.0f / (e2 + 1.0f);       // tanh(s)
                float f  = f_in[idx];
                float hp = ZERO ? 0.0f : h_buf[idx];
                float h  = (1.0f - f) * hp + f * g;
                float d  = h - thr;
                bool  e  = d > 0.0f;
                float y  = e ? h : 0.0f;
                ys[idx] = y;
                ev[idx] = e ? 1.0f : 0.0f;
                nd[idx] = (d < 0.0f) ? (thr - h) : 0.0f;
                h_buf[idx] = e ? d : h;                     // h - event*thr
                pk[r] = pack2(y);
            }
            *(uint4*)&y_pack[(((size_t)n * 64 + row) * 64 + col) * 64
                             + ch * 32 + ct * 16 + lg * 4] =
                make_uint4(pk[0], pk[1], pk[2], pk[3]);
        }
}

// ---------------------------------------------------------------------------
extern "C" void kernel_launch(void* const* d_in, const int* in_sizes, int n_in,
                              void* d_out, int out_size, void* d_ws, size_t ws_size,
                              hipStream_t stream) {
    (void)in_sizes; (void)n_in; (void)out_size; (void)ws_size;

    const float* xt     = (const float*)d_in[0];
    const float* w_rz   = (const float*)d_in[1];
    const float* b_rz   = (const float*)d_in[2];
    const float* w_f    = (const float*)d_in[3];
    const float* b_f    = (const float*)d_in[4];
    const float* thr_rp = (const float*)d_in[5];

    float* out = (float*)d_out;
    float*    h_buf  = (float*)d_ws;                      // NCHW f32
    float*    f_buf  = h_buf + NCHW;                      // NCHW f32
    uint32_t* a_pack = (uint32_t*)(f_buf + NCHW);         // NCHW u32
    uint32_t* y_pack = a_pack + NCHW;                     // NCHW u32
    uint32_t* wpack  = y_pack + NCHW;                     // 73728 u32

    float* ys0 = out;
    float* ev0 = out + (size_t)T_STEPS * NCHW;
    float* nd0 = ev0 + (size_t)T_STEPS * NCHW;

    prep_w<<<288, 256, 0, stream>>>(w_rz, w_f, wpack);

    const uint32_t* wpkA = wpack;                         // w_rz
    const uint32_t* wpkB = wpack + 9 * 4096;              // w_f

    dim3 grid(512), block(256);
    for (int t = 0; t < T_STEPS; ++t) {
        const float* xt_t = xt + (size_t)t * XTSTR;
        float* ys_t = ys0 + (size_t)t * NCHW;
        float* ev_t = ev0 + (size_t)t * NCHW;
        float* nd_t = nd0 + (size_t)t * NCHW;
        if (t == 0) {
            kA<true><<<grid, block, 0, stream>>>(nullptr, nullptr, wpkA, b_rz, xt_t,
                                                 f_buf, a_pack);
            kB<true><<<grid, block, 0, stream>>>(a_pack, wpkB, b_f, xt_t, f_buf, thr_rp,
                                                 h_buf, ys_t, ev_t, nd_t, y_pack);
        } else {
            const float* yprev = ys0 + (size_t)(t - 1) * NCHW;
            kA<false><<<grid, block, 0, stream>>>(yprev, y_pack, wpkA, b_rz, xt_t,
                                                  f_buf, a_pack);
            kB<false><<<grid, block, 0, stream>>>(a_pack, wpkB, b_f, xt_t, f_buf, thr_rp,
                                                  h_buf, ys_t, ev_t, nd_t, y_pack);
        }
    }
}